// Round 1
// baseline (249.450 us; speedup 1.0000x reference)
//
#include <hip/hip_runtime.h>
#include <hip/hip_bf16.h>

#define BATCH  4096
#define INF    1024
#define OUTF   1024
#define KSPL   11
#define KTOT   12288   /* 1024 silu cols + 11*1024 spline cols (k-major) */
#define NSPLIT 3
#define KSPLIT 4096    /* KTOT / NSPLIT */

using bf16    = __hip_bfloat16;
using short8  = __attribute__((ext_vector_type(8))) short;
using ushort8 = __attribute__((ext_vector_type(8))) unsigned short;
using f32x4   = __attribute__((ext_vector_type(4))) float;

__device__ __forceinline__ unsigned short f2bf(float f){
  union { float f; unsigned u; } a; a.f = f;
  return (unsigned short)((a.u + 0x7FFFu + ((a.u >> 16) & 1u)) >> 16); // RNE
}

__device__ __forceinline__ void llds16(const void* g, void* l){
  __builtin_amdgcn_global_load_lds(
      (const __attribute__((address_space(1))) unsigned int*)g,
      (__attribute__((address_space(3))) unsigned int*)l, 16, 0, 0);
}

// ---------------------------------------------------------------------------
// A[b][kt] bf16: kt<1024 -> silu(x[b,kt]); kt=1024+k*1024+i -> basis(b,i,k)
// basis one-hot in k: cell = floor((x+1)/h)+3, val = sin(pi*frac)
// ---------------------------------------------------------------------------
__global__ __launch_bounds__(128) void gen_a(const float* __restrict__ x,
                                             bf16* __restrict__ A){
  const int b = blockIdx.x, t = threadIdx.x;
  const float* xr = x + (size_t)b * INF;
  bf16* ar = A + (size_t)b * KTOT;
  const int i0 = t * 8;
  f32x4 p0 = *(const f32x4*)(xr + i0);
  f32x4 p1 = *(const f32x4*)(xr + i0 + 4);
  float v[8];
  #pragma unroll
  for (int j = 0; j < 4; ++j){ v[j] = p0[j]; v[4+j] = p1[j]; }
  ushort8 sl;
  int   c[8];
  float sg[8];
  #pragma unroll
  for (int j = 0; j < 8; ++j){
    float xx = v[j];
    sl[j] = f2bf(xx / (1.0f + __expf(-xx)));
    float tt = (xx + 1.0f) * 2.5f;         // (x - (-1)) / 0.4
    float fl = floorf(tt);
    c[j]  = (int)fl + 3;
    sg[j] = __sinf(3.14159265358979f * (tt - fl));
  }
  *(ushort8*)(ar + i0) = sl;
  #pragma unroll
  for (int k = 0; k < KSPL; ++k){
    ushort8 ov;
    #pragma unroll
    for (int j = 0; j < 8; ++j)
      ov[j] = (c[j] == k) ? f2bf(sg[j]) : (unsigned short)0;
    *(ushort8*)(ar + INF + k*INF + i0) = ov;
  }
}

// ---------------------------------------------------------------------------
// W[o][kt] bf16: kt<1024 -> base_weight[o,kt];
//               kt=1024+k*1024+i -> spline_weight[o,i,k]*spline_scaler[o,i]
// LDS-staged transpose so global reads AND writes are coalesced.
// ---------------------------------------------------------------------------
__global__ __launch_bounds__(128) void pack_w(const float* __restrict__ bw,
                                              const float* __restrict__ sw,
                                              const float* __restrict__ sc,
                                              bf16* __restrict__ W){
  const int o = blockIdx.x, t = threadIdx.x;
  __shared__ float lsw[INF * KSPL];   // 44 KB
  __shared__ float lsc[INF];          // 4 KB
  const float* swo = sw + (size_t)o * INF * KSPL;
  for (int idx = t; idx < INF*KSPL/4; idx += 128)
    ((f32x4*)lsw)[idx] = ((const f32x4*)swo)[idx];
  for (int idx = t; idx < INF/4; idx += 128)
    ((f32x4*)lsc)[idx] = ((const f32x4*)(sc + (size_t)o*INF))[idx];
  __syncthreads();
  bf16* wrow = W + (size_t)o * KTOT;
  const int i0 = t * 8;
  {
    const float* br = bw + (size_t)o*INF + i0;
    f32x4 v0 = *(const f32x4*)br;
    f32x4 v1 = *(const f32x4*)(br + 4);
    ushort8 u;
    #pragma unroll
    for (int j = 0; j < 4; ++j){ u[j] = f2bf(v0[j]); u[4+j] = f2bf(v1[j]); }
    *(ushort8*)(wrow + i0) = u;
  }
  #pragma unroll
  for (int k = 0; k < KSPL; ++k){
    ushort8 u;
    #pragma unroll
    for (int j = 0; j < 8; ++j)
      u[j] = f2bf(lsw[(i0 + j)*KSPL + k] * lsc[i0 + j]);
    *(ushort8*)(wrow + INF + k*INF + i0) = u;
  }
}

// ---------------------------------------------------------------------------
// C = A @ W^T   (m97-style 128x128 tile, BK=64, 4 waves 2x2, K-split x3)
// ---------------------------------------------------------------------------
__global__ __launch_bounds__(256) void gemm_bt(const bf16* __restrict__ A,
                                               const bf16* __restrict__ W,
                                               float* __restrict__ Cp){
  __shared__ __align__(16) bf16 al[128*64];
  __shared__ __align__(16) bf16 bl[128*64];
  int bid = blockIdx.x;
  bid = (bid & 7) * 96 + (bid >> 3);         // XCD swizzle (768 % 8 == 0)
  const int split = bid >> 8;                // 0..2
  const int rem   = bid & 255;
  const int bm = (rem & 31) * 128;
  const int bn = (rem >> 5) * 128;
  const int t    = threadIdx.x;
  const int lane = t & 63;
  const int wv   = t >> 6;
  const int wr = wv >> 1, wc = wv & 1;
  f32x4 acc[4][4] = {};
  const size_t k0base = (size_t)split * KSPLIT;

  for (int it = 0; it < KSPLIT/64; ++it){
    const size_t k0 = k0base + (size_t)it*64;
    #pragma unroll
    for (int j = 0; j < 4; ++j){
      const int s = t + 256*j;               // 16B slot id, lane-consecutive per wave
      const int row = s >> 3, c16 = s & 7;
      llds16(A + (size_t)(bm + row)*KTOT + k0 + c16*8, al + (wv*64 + 256*j)*8);
      llds16(W + (size_t)(bn + row)*KTOT + k0 + c16*8, bl + (wv*64 + 256*j)*8);
    }
    __syncthreads();                         // drains vmcnt before barrier
    #pragma unroll
    for (int ks = 0; ks < 2; ++ks){
      short8 af[4], bfv[4];
      #pragma unroll
      for (int m = 0; m < 4; ++m){
        const int row = wr*64 + m*16 + (lane & 15);
        af[m] = *(const short8*)(al + row*64 + ks*32 + (lane >> 4)*8);
      }
      #pragma unroll
      for (int n = 0; n < 4; ++n){
        const int col = wc*64 + n*16 + (lane & 15);
        bfv[n] = *(const short8*)(bl + col*64 + ks*32 + (lane >> 4)*8);
      }
      #pragma unroll
      for (int m = 0; m < 4; ++m)
        #pragma unroll
        for (int n = 0; n < 4; ++n)
          acc[m][n] = __builtin_amdgcn_mfma_f32_16x16x32_bf16(af[m], bfv[n], acc[m][n], 0, 0, 0);
    }
    __syncthreads();
  }

  float* outp = Cp + (size_t)split * BATCH * OUTF;
  #pragma unroll
  for (int m = 0; m < 4; ++m){
    const int r0 = bm + wr*64 + m*16 + ((lane >> 4) << 2);
    #pragma unroll
    for (int n = 0; n < 4; ++n){
      const int cc = bn + wc*64 + n*16 + (lane & 15);
      #pragma unroll
      for (int j = 0; j < 4; ++j)
        outp[(size_t)(r0 + j) * OUTF + cc] = acc[m][n][j];
    }
  }
}

__global__ __launch_bounds__(256) void reduce3(const float* __restrict__ Cp,
                                               float* __restrict__ out){
  const size_t idx = ((size_t)blockIdx.x * 256 + threadIdx.x) * 4;
  const size_t NN  = (size_t)BATCH * OUTF;
  f32x4 a = *(const f32x4*)(Cp + idx);
  f32x4 b = *(const f32x4*)(Cp + NN + idx);
  f32x4 c = *(const f32x4*)(Cp + 2*NN + idx);
  *(f32x4*)(out + idx) = a + b + c;
}

// Correct-but-slow safety net if ws_size is smaller than expected.
__global__ __launch_bounds__(256) void fallback(const float* __restrict__ x,
    const float* __restrict__ bw, const float* __restrict__ sw,
    const float* __restrict__ sc, float* __restrict__ out){
  const int b = blockIdx.x, t = threadIdx.x;
  __shared__ float ls[INF], sg[INF];
  __shared__ int   lc[INF];
  for (int i = t; i < INF; i += 256){
    float xx = x[(size_t)b*INF + i];
    ls[i] = xx / (1.0f + __expf(-xx));
    float tt = (xx + 1.0f)*2.5f;
    float fl = floorf(tt);
    int c = (int)fl + 3;
    lc[i] = ((unsigned)c < 11u) ? c : -1;
    sg[i] = __sinf(3.14159265358979f*(tt - fl));
  }
  __syncthreads();
  for (int o = t; o < OUTF; o += 256){
    float acc = 0.f;
    const float* bwr = bw + (size_t)o*INF;
    const float* swr = sw + (size_t)o*INF*KSPL;
    const float* scr = sc + (size_t)o*INF;
    for (int i = 0; i < INF; ++i){
      acc = fmaf(ls[i], bwr[i], acc);
      int c = lc[i];
      if (c >= 0) acc = fmaf(sg[i]*scr[i], swr[i*KSPL + c], acc);
    }
    out[(size_t)b*OUTF + o] = acc;
  }
}

extern "C" void kernel_launch(void* const* d_in, const int* in_sizes, int n_in,
                              void* d_out, int out_size, void* d_ws, size_t ws_size,
                              hipStream_t stream){
  const float* x  = (const float*)d_in[0];
  const float* bw = (const float*)d_in[1];
  const float* sw = (const float*)d_in[2];
  const float* sc = (const float*)d_in[3];
  float* out = (float*)d_out;
  const size_t szA = (size_t)BATCH * KTOT * 2;            // 100.7 MB
  const size_t szW = (size_t)OUTF  * KTOT * 2;            //  25.2 MB
  const size_t szP = (size_t)NSPLIT * BATCH * OUTF * 4;   //  50.3 MB
  if (ws_size >= szA + szW + szP){
    bf16*  A  = (bf16*)d_ws;
    bf16*  W  = (bf16*)((char*)d_ws + szA);
    float* Cp = (float*)((char*)d_ws + szA + szW);
    hipLaunchKernelGGL(gen_a,   dim3(BATCH), dim3(128), 0, stream, x, A);
    hipLaunchKernelGGL(pack_w,  dim3(OUTF),  dim3(128), 0, stream, bw, sw, sc, W);
    hipLaunchKernelGGL(gemm_bt, dim3(768),   dim3(256), 0, stream, A, W, Cp);
    hipLaunchKernelGGL(reduce3, dim3(4096),  dim3(256), 0, stream, Cp, out);
  } else {
    hipLaunchKernelGGL(fallback, dim3(BATCH), dim3(256), 0, stream, x, bw, sw, sc, out);
  }
}

// Round 2
// 163.250 us; speedup vs baseline: 1.5280x; 1.5280x over previous
//
#include <hip/hip_runtime.h>
#include <hip/hip_bf16.h>

#define BATCH  4096
#define INF    1024
#define OUTF   1024
#define KSPL   11
#define KTOT   12288   /* 1024 silu cols + 11*1024 spline cols (k-major) */

using bf16    = __hip_bfloat16;
using short8  = __attribute__((ext_vector_type(8))) short;
using ushort8 = __attribute__((ext_vector_type(8))) unsigned short;
using f32x4   = __attribute__((ext_vector_type(4))) float;

__device__ __forceinline__ unsigned short f2bf(float f){
  union { float f; unsigned u; } a; a.f = f;
  return (unsigned short)((a.u + 0x7FFFu + ((a.u >> 16) & 1u)) >> 16); // RNE
}

__device__ __forceinline__ void llds16(const void* g, const void* l){
  __builtin_amdgcn_global_load_lds(
      (const __attribute__((address_space(1))) unsigned int*)g,
      (__attribute__((address_space(3))) unsigned int*)l, 16, 0, 0);
}

__device__ __forceinline__ void bar(){
  asm volatile("" ::: "memory");
  __builtin_amdgcn_s_barrier();
  asm volatile("" ::: "memory");
}

__device__ __forceinline__ f32x4 mfma16(short8 a, short8 b, f32x4 c){
  return __builtin_amdgcn_mfma_f32_16x16x32_bf16(a, b, c, 0, 0, 0);
}

// ---------------------------------------------------------------------------
// A[b][kt] bf16: kt<1024 -> silu(x[b,kt]); kt=1024+k*1024+i -> basis(b,i,k)
// ---------------------------------------------------------------------------
__global__ __launch_bounds__(128) void gen_a(const float* __restrict__ x,
                                             bf16* __restrict__ A){
  const int b = blockIdx.x, t = threadIdx.x;
  const float* xr = x + (size_t)b * INF;
  bf16* ar = A + (size_t)b * KTOT;
  const int i0 = t * 8;
  f32x4 p0 = *(const f32x4*)(xr + i0);
  f32x4 p1 = *(const f32x4*)(xr + i0 + 4);
  float v[8];
  #pragma unroll
  for (int j = 0; j < 4; ++j){ v[j] = p0[j]; v[4+j] = p1[j]; }
  ushort8 sl;
  int   c[8];
  float sg[8];
  #pragma unroll
  for (int j = 0; j < 8; ++j){
    float xx = v[j];
    sl[j] = f2bf(xx / (1.0f + __expf(-xx)));
    float tt = (xx + 1.0f) * 2.5f;
    float fl = floorf(tt);
    c[j]  = (int)fl + 3;
    sg[j] = __sinf(3.14159265358979f * (tt - fl));
  }
  *(ushort8*)(ar + i0) = sl;
  #pragma unroll
  for (int k = 0; k < KSPL; ++k){
    ushort8 ov;
    #pragma unroll
    for (int j = 0; j < 8; ++j)
      ov[j] = (c[j] == k) ? f2bf(sg[j]) : (unsigned short)0;
    *(ushort8*)(ar + INF + k*INF + i0) = ov;
  }
}

// ---------------------------------------------------------------------------
// W[o][kt] bf16 pack (same as round 1, validated)
// ---------------------------------------------------------------------------
__global__ __launch_bounds__(128) void pack_w(const float* __restrict__ bw,
                                              const float* __restrict__ sw,
                                              const float* __restrict__ sc,
                                              bf16* __restrict__ W){
  const int o = blockIdx.x, t = threadIdx.x;
  __shared__ float lsw[INF * KSPL];
  __shared__ float lsc[INF];
  const float* swo = sw + (size_t)o * INF * KSPL;
  for (int idx = t; idx < INF*KSPL/4; idx += 128)
    ((f32x4*)lsw)[idx] = ((const f32x4*)swo)[idx];
  for (int idx = t; idx < INF/4; idx += 128)
    ((f32x4*)lsc)[idx] = ((const f32x4*)(sc + (size_t)o*INF))[idx];
  __syncthreads();
  bf16* wrow = W + (size_t)o * KTOT;
  const int i0 = t * 8;
  {
    const float* br = bw + (size_t)o*INF + i0;
    f32x4 v0 = *(const f32x4*)br;
    f32x4 v1 = *(const f32x4*)(br + 4);
    ushort8 u;
    #pragma unroll
    for (int j = 0; j < 4; ++j){ u[j] = f2bf(v0[j]); u[4+j] = f2bf(v1[j]); }
    *(ushort8*)(wrow + i0) = u;
  }
  #pragma unroll
  for (int k = 0; k < KSPL; ++k){
    ushort8 u;
    #pragma unroll
    for (int j = 0; j < 8; ++j)
      u[j] = f2bf(lsw[(i0 + j)*KSPL + k] * lsc[i0 + j]);
    *(ushort8*)(wrow + INF + k*INF + i0) = u;
  }
}

// ---------------------------------------------------------------------------
// Deep-pipelined GEMM: C = A @ W^T, 256x256 tile, BK=32, 4 LDS bufs,
// counted vmcnt(8), T2 XOR-swizzle, T5 setprio. Split-K = NS.
// Buf layout: buf*32768 + {A:0, B:16384} + phys. phys = L ^ ((L>>7&7)<<4),
// L = row*64 + hi*16 (row stride 64B = BK*2). Involution: XOR touches bits
// 4-6 only; F reads bits 7-9 -> read/write permutations match.
// Schedule safety: group t stages tile t+3 into buf (t+3)&3 = (t-1)&3, whose
// last reads (tile t-1) completed before the group t-1 end barrier.
// ---------------------------------------------------------------------------
template<int NS>
__global__ __launch_bounds__(512, 2) void gemm8p(const bf16* __restrict__ A,
                                                 const bf16* __restrict__ W,
                                                 float* __restrict__ Cp){
  constexpr int KSPLIT = KTOT / NS;
  constexpr int NG     = KSPLIT / 32;
  constexpr int NWG    = 16 * 4 * NS;
  __shared__ __align__(16) char smem[131072];

  int bid = blockIdx.x;
  const int fin = (bid & 7) * (NWG/8) + (bid >> 3);   // XCD swizzle (NWG%8==0)
  const int mt = fin / (4*NS);
  const int rr = fin % (4*NS);
  const int nt = rr / NS;
  const int split = rr % NS;
  const int bm = mt*256, bn = nt*256;

  const int t    = threadIdx.x;
  const int lane = t & 63, w = t >> 6;
  const int wr = w >> 2, wc = w & 3;            // 2 x 4 wave grid
  const int r15 = lane & 15, hi = lane >> 4;

  // per-thread constant swizzled ds_read byte offsets
  int offA[8], offB[4];
  #pragma unroll
  for (int m = 0; m < 8; ++m){
    int L = (wr*128 + m*16 + r15)*64 + hi*16;
    offA[m] = L ^ (((L>>7)&7)<<4);
  }
  #pragma unroll
  for (int n = 0; n < 4; ++n){
    int L = (wc*64 + n*16 + r15)*64 + hi*16;
    offB[n] = 16384 + (L ^ (((L>>7)&7)<<4));
  }

  // stage source pointers (inverse-swizzled global addresses) + uniform dests
  const char* gA[2]; const char* gB[2];
  int ldsA[2], ldsB[2];
  #pragma unroll
  for (int j = 0; j < 2; ++j){
    int P = (t + j*512)*16;
    int L = P ^ (((P>>7)&7)<<4);
    int row = L >> 6, inner = L & 63;
    gA[j] = (const char*)A + ((size_t)(bm + row)*KTOT + (size_t)split*KSPLIT)*2 + inner;
    gB[j] = (const char*)W + ((size_t)(bn + row)*KTOT + (size_t)split*KSPLIT)*2 + inner;
    ldsA[j] = j*8192 + w*1024;
    ldsB[j] = 16384 + j*8192 + w*1024;
  }

  #define STAGE_A(buf, tile) do{ \
    llds16(gA[0] + (tile)*64, smem + (buf)*32768 + ldsA[0]); \
    llds16(gA[1] + (tile)*64, smem + (buf)*32768 + ldsA[1]); }while(0)
  #define STAGE_B(buf, tile) do{ \
    llds16(gB[0] + (tile)*64, smem + (buf)*32768 + ldsB[0]); \
    llds16(gB[1] + (tile)*64, smem + (buf)*32768 + ldsB[1]); }while(0)

  f32x4 acc[8][4] = {};

  // prologue: stage tiles 0,1,2 (12 loads); wait tile 0 (leave 8 in flight)
  STAGE_A(0,0); STAGE_B(0,0);
  STAGE_A(1,1); STAGE_B(1,1);
  STAGE_A(2,2); STAGE_B(2,2);
  asm volatile("s_waitcnt vmcnt(8)" ::: "memory");
  bar();

  for (int tile = 0; tile < NG; ++tile){
    const int buf = tile & 3;
    const char* bp = smem + buf*32768;
    short8 af[8], bf2[2];
    // ---- phase A: all A-frags + B n0,n1; stage next A-half
    #pragma unroll
    for (int m = 0; m < 8; ++m) af[m] = *(const short8*)(bp + offA[m]);
    bf2[0] = *(const short8*)(bp + offB[0]);
    bf2[1] = *(const short8*)(bp + offB[1]);
    if (tile < NG-3) STAGE_A((tile+3)&3, tile+3);
    bar();
    __builtin_amdgcn_s_setprio(1);
    #pragma unroll
    for (int m = 0; m < 8; ++m){
      acc[m][0] = mfma16(af[m], bf2[0], acc[m][0]);
      acc[m][1] = mfma16(af[m], bf2[1], acc[m][1]);
    }
    __builtin_amdgcn_s_setprio(0);
    bar();
    // ---- phase B: B n2,n3; stage next B-half; counted vmcnt
    bf2[0] = *(const short8*)(bp + offB[2]);
    bf2[1] = *(const short8*)(bp + offB[3]);
    if (tile < NG-3) STAGE_B((tile+3)&3, tile+3);
    if (tile < NG-3)      asm volatile("s_waitcnt vmcnt(8)" ::: "memory");
    else if (tile == NG-3) asm volatile("s_waitcnt vmcnt(4)" ::: "memory");
    else if (tile == NG-2) asm volatile("s_waitcnt vmcnt(0)" ::: "memory");
    bar();
    __builtin_amdgcn_s_setprio(1);
    #pragma unroll
    for (int m = 0; m < 8; ++m){
      acc[m][2] = mfma16(af[m], bf2[0], acc[m][2]);
      acc[m][3] = mfma16(af[m], bf2[1], acc[m][3]);
    }
    __builtin_amdgcn_s_setprio(0);
    bar();
  }
  #undef STAGE_A
  #undef STAGE_B

  float* outp = Cp + (size_t)split * (BATCH*OUTF);
  #pragma unroll
  for (int m = 0; m < 8; ++m){
    const int r0 = bm + wr*128 + m*16 + hi*4;
    #pragma unroll
    for (int n = 0; n < 4; ++n){
      const int cc = bn + wc*64 + n*16 + r15;
      #pragma unroll
      for (int j = 0; j < 4; ++j)
        outp[(size_t)(r0 + j) * OUTF + cc] = acc[m][n][j];
    }
  }
}

template<int NS>
__global__ __launch_bounds__(256) void reduceNS(const float* __restrict__ Cp,
                                                float* __restrict__ out){
  const size_t idx = ((size_t)blockIdx.x * 256 + threadIdx.x) * 4;
  f32x4 s = *(const f32x4*)(Cp + idx);
  #pragma unroll
  for (int p = 1; p < NS; ++p)
    s += *(const f32x4*)(Cp + (size_t)p * (BATCH*OUTF) + idx);
  *(f32x4*)(out + idx) = s;
}

// Correct-but-slow safety net if ws_size is tiny.
__global__ __launch_bounds__(256) void fallback(const float* __restrict__ x,
    const float* __restrict__ bw, const float* __restrict__ sw,
    const float* __restrict__ sc, float* __restrict__ out){
  const int b = blockIdx.x, t = threadIdx.x;
  __shared__ float ls[INF], sg[INF];
  __shared__ int   lc[INF];
  for (int i = t; i < INF; i += 256){
    float xx = x[(size_t)b*INF + i];
    ls[i] = xx / (1.0f + __expf(-xx));
    float tt = (xx + 1.0f)*2.5f;
    float fl = floorf(tt);
    int c = (int)fl + 3;
    lc[i] = ((unsigned)c < 11u) ? c : -1;
    sg[i] = __sinf(3.14159265358979f*(tt - fl));
  }
  __syncthreads();
  for (int o = t; o < OUTF; o += 256){
    float acc = 0.f;
    const float* bwr = bw + (size_t)o*INF;
    const float* swr = sw + (size_t)o*INF*KSPL;
    const float* scr = sc + (size_t)o*INF;
    for (int i = 0; i < INF; ++i){
      acc = fmaf(ls[i], bwr[i], acc);
      int c = lc[i];
      if (c >= 0) acc = fmaf(sg[i]*scr[i], swr[i*KSPL + c], acc);
    }
    out[(size_t)b*OUTF + o] = acc;
  }
}

extern "C" void kernel_launch(void* const* d_in, const int* in_sizes, int n_in,
                              void* d_out, int out_size, void* d_ws, size_t ws_size,
                              hipStream_t stream){
  const float* x  = (const float*)d_in[0];
  const float* bw = (const float*)d_in[1];
  const float* sw = (const float*)d_in[2];
  const float* sc = (const float*)d_in[3];
  float* out = (float*)d_out;
  const size_t szA = (size_t)BATCH * KTOT * 2;   // 100.7 MB
  const size_t szW = (size_t)OUTF  * KTOT * 2;   //  25.2 MB
  const size_t szC = (size_t)BATCH * OUTF * 4;   //  16.8 MB per split
  bf16*  A  = (bf16*)d_ws;
  bf16*  W  = (bf16*)((char*)d_ws + szA);
  float* Cp = (float*)((char*)d_ws + szA + szW);
  if (ws_size >= szA + szW + 4*szC){
    hipLaunchKernelGGL(gen_a,  dim3(BATCH), dim3(128), 0, stream, x, A);
    hipLaunchKernelGGL(pack_w, dim3(OUTF),  dim3(128), 0, stream, bw, sw, sc, W);
    gemm8p<4><<<dim3(256), dim3(512), 0, stream>>>(A, W, Cp);
    reduceNS<4><<<dim3(4096), dim3(256), 0, stream>>>(Cp, out);
  } else if (ws_size >= szA + szW + 3*szC){
    hipLaunchKernelGGL(gen_a,  dim3(BATCH), dim3(128), 0, stream, x, A);
    hipLaunchKernelGGL(pack_w, dim3(OUTF),  dim3(128), 0, stream, bw, sw, sc, W);
    gemm8p<3><<<dim3(192), dim3(512), 0, stream>>>(A, W, Cp);
    reduceNS<3><<<dim3(4096), dim3(256), 0, stream>>>(Cp, out);
  } else {
    hipLaunchKernelGGL(fallback, dim3(BATCH), dim3(256), 0, stream, x, bw, sw, sc, out);
  }
}

// Round 3
// 162.104 us; speedup vs baseline: 1.5388x; 1.0071x over previous
//
#include <hip/hip_runtime.h>
#include <hip/hip_bf16.h>

#define BATCH  4096
#define INF    1024
#define OUTF   1024
#define KSPL   11
#define KTOT   12288   /* 1024 silu cols + 11*1024 spline cols (k-major) */

using bf16    = __hip_bfloat16;
using short8  = __attribute__((ext_vector_type(8))) short;
using ushort8 = __attribute__((ext_vector_type(8))) unsigned short;
using f32x4   = __attribute__((ext_vector_type(4))) float;

__device__ __forceinline__ unsigned short f2bf(float f){
  union { float f; unsigned u; } a; a.f = f;
  return (unsigned short)((a.u + 0x7FFFu + ((a.u >> 16) & 1u)) >> 16); // RNE
}

__device__ __forceinline__ void llds16(const void* g, const void* l){
  __builtin_amdgcn_global_load_lds(
      (const __attribute__((address_space(1))) unsigned int*)g,
      (__attribute__((address_space(3))) unsigned int*)l, 16, 0, 0);
}

__device__ __forceinline__ void bar(){
  asm volatile("" ::: "memory");
  __builtin_amdgcn_s_barrier();
  asm volatile("" ::: "memory");
}

__device__ __forceinline__ f32x4 mfma16(short8 a, short8 b, f32x4 c){
  return __builtin_amdgcn_mfma_f32_16x16x32_bf16(a, b, c, 0, 0, 0);
}

// ---------------------------------------------------------------------------
// A[b][kt] bf16: kt<1024 -> silu(x[b,kt]); kt=1024+k*1024+i -> basis(b,i,k)
// ---------------------------------------------------------------------------
__global__ __launch_bounds__(128) void gen_a(const float* __restrict__ x,
                                             bf16* __restrict__ A){
  const int b = blockIdx.x, t = threadIdx.x;
  const float* xr = x + (size_t)b * INF;
  bf16* ar = A + (size_t)b * KTOT;
  const int i0 = t * 8;
  f32x4 p0 = *(const f32x4*)(xr + i0);
  f32x4 p1 = *(const f32x4*)(xr + i0 + 4);
  float v[8];
  #pragma unroll
  for (int j = 0; j < 4; ++j){ v[j] = p0[j]; v[4+j] = p1[j]; }
  ushort8 sl;
  int   c[8];
  float sg[8];
  #pragma unroll
  for (int j = 0; j < 8; ++j){
    float xx = v[j];
    sl[j] = f2bf(xx / (1.0f + __expf(-xx)));
    float tt = (xx + 1.0f) * 2.5f;
    float fl = floorf(tt);
    c[j]  = (int)fl + 3;
    sg[j] = __sinf(3.14159265358979f * (tt - fl));
  }
  *(ushort8*)(ar + i0) = sl;
  #pragma unroll
  for (int k = 0; k < KSPL; ++k){
    ushort8 ov;
    #pragma unroll
    for (int j = 0; j < 8; ++j)
      ov[j] = (c[j] == k) ? f2bf(sg[j]) : (unsigned short)0;
    *(ushort8*)(ar + INF + k*INF + i0) = ov;
  }
}

// ---------------------------------------------------------------------------
// W[o][kt] bf16 pack (validated)
// ---------------------------------------------------------------------------
__global__ __launch_bounds__(128) void pack_w(const float* __restrict__ bw,
                                              const float* __restrict__ sw,
                                              const float* __restrict__ sc,
                                              bf16* __restrict__ W){
  const int o = blockIdx.x, t = threadIdx.x;
  __shared__ float lsw[INF * KSPL];
  __shared__ float lsc[INF];
  const float* swo = sw + (size_t)o * INF * KSPL;
  for (int idx = t; idx < INF*KSPL/4; idx += 128)
    ((f32x4*)lsw)[idx] = ((const f32x4*)swo)[idx];
  for (int idx = t; idx < INF/4; idx += 128)
    ((f32x4*)lsc)[idx] = ((const f32x4*)(sc + (size_t)o*INF))[idx];
  __syncthreads();
  bf16* wrow = W + (size_t)o * KTOT;
  const int i0 = t * 8;
  {
    const float* br = bw + (size_t)o*INF + i0;
    f32x4 v0 = *(const f32x4*)br;
    f32x4 v1 = *(const f32x4*)(br + 4);
    ushort8 u;
    #pragma unroll
    for (int j = 0; j < 4; ++j){ u[j] = f2bf(v0[j]); u[4+j] = f2bf(v1[j]); }
    *(ushort8*)(wrow + i0) = u;
  }
  #pragma unroll
  for (int k = 0; k < KSPL; ++k){
    ushort8 u;
    #pragma unroll
    for (int j = 0; j < 8; ++j)
      u[j] = f2bf(lsw[(i0 + j)*KSPL + k] * lsc[i0 + j]);
    *(ushort8*)(wrow + INF + k*INF + i0) = u;
  }
}

// ---------------------------------------------------------------------------
// Deep-pipelined GEMM: C = A @ W^T, 256x256 tile, BK=32, 4 LDS bufs,
// counted vmcnt(8), T2 XOR-swizzle, T5 setprio. Split-K = NS.
// Round-3 change: all 12 ds_read_b128 issued at phase-A top; phase-A MFMA
// (acc[0..3][*]) depends on the first 8 only (compiler emits counted
// lgkmcnt); phase B is a pure-register MFMA cluster (acc[4..7][*]) so the
// af[4..7] drain and STAGE_B+vmcnt hide under MFMA.
// Schedule safety (unchanged): group t stages tile t+3 into buf (t-1)&3,
// whose last reads finished before the end-of-tile-(t-1) barrier.
// ---------------------------------------------------------------------------
template<int NS>
__global__ __launch_bounds__(512, 2) void gemm8p(const bf16* __restrict__ A,
                                                 const bf16* __restrict__ W,
                                                 float* __restrict__ Cp){
  constexpr int KSPLIT = KTOT / NS;
  constexpr int NG     = KSPLIT / 32;
  constexpr int NWG    = 16 * 4 * NS;
  __shared__ __align__(16) char smem[131072];

  int bid = blockIdx.x;
  const int fin = (bid & 7) * (NWG/8) + (bid >> 3);   // XCD swizzle (NWG%8==0)
  const int mt = fin / (4*NS);
  const int rr = fin % (4*NS);
  const int nt = rr / NS;
  const int split = rr % NS;
  const int bm = mt*256, bn = nt*256;

  const int t    = threadIdx.x;
  const int lane = t & 63, w = t >> 6;
  const int wr = w >> 2, wc = w & 3;            // 2 x 4 wave grid
  const int r15 = lane & 15, hi = lane >> 4;

  // per-thread constant swizzled ds_read byte offsets
  int offA[8], offB[4];
  #pragma unroll
  for (int m = 0; m < 8; ++m){
    int L = (wr*128 + m*16 + r15)*64 + hi*16;
    offA[m] = L ^ (((L>>7)&7)<<4);
  }
  #pragma unroll
  for (int n = 0; n < 4; ++n){
    int L = (wc*64 + n*16 + r15)*64 + hi*16;
    offB[n] = 16384 + (L ^ (((L>>7)&7)<<4));
  }

  // stage source pointers (inverse-swizzled global addresses) + uniform dests
  const char* gA[2]; const char* gB[2];
  int ldsA[2], ldsB[2];
  #pragma unroll
  for (int j = 0; j < 2; ++j){
    int P = (t + j*512)*16;
    int L = P ^ (((P>>7)&7)<<4);
    int row = L >> 6, inner = L & 63;
    gA[j] = (const char*)A + ((size_t)(bm + row)*KTOT + (size_t)split*KSPLIT)*2 + inner;
    gB[j] = (const char*)W + ((size_t)(bn + row)*KTOT + (size_t)split*KSPLIT)*2 + inner;
    ldsA[j] = j*8192 + w*1024;
    ldsB[j] = 16384 + j*8192 + w*1024;
  }

  #define STAGE_A(buf, tile) do{ \
    llds16(gA[0] + (tile)*64, smem + (buf)*32768 + ldsA[0]); \
    llds16(gA[1] + (tile)*64, smem + (buf)*32768 + ldsA[1]); }while(0)
  #define STAGE_B(buf, tile) do{ \
    llds16(gB[0] + (tile)*64, smem + (buf)*32768 + ldsB[0]); \
    llds16(gB[1] + (tile)*64, smem + (buf)*32768 + ldsB[1]); }while(0)

  f32x4 acc[8][4] = {};

  // prologue: stage tiles 0,1,2 (12 loads); wait tile 0 (leave 8 in flight)
  STAGE_A(0,0); STAGE_B(0,0);
  STAGE_A(1,1); STAGE_B(1,1);
  STAGE_A(2,2); STAGE_B(2,2);
  asm volatile("s_waitcnt vmcnt(8)" ::: "memory");
  bar();

  for (int tile = 0; tile < NG; ++tile){
    const int buf = tile & 3;
    const char* bp = smem + buf*32768;
    short8 af[4], ag[4], bf4[4];
    // ---- phase A: issue ALL 12 reads; stage next A-half; MFMA m=0..3
    #pragma unroll
    for (int m = 0; m < 4; ++m) af[m]  = *(const short8*)(bp + offA[m]);
    #pragma unroll
    for (int n = 0; n < 4; ++n) bf4[n] = *(const short8*)(bp + offB[n]);
    #pragma unroll
    for (int m = 0; m < 4; ++m) ag[m]  = *(const short8*)(bp + offA[4+m]);
    if (tile < NG-3) STAGE_A((tile+3)&3, tile+3);
    bar();
    __builtin_amdgcn_s_setprio(1);
    #pragma unroll
    for (int m = 0; m < 4; ++m)
      #pragma unroll
      for (int n = 0; n < 4; ++n)
        acc[m][n] = mfma16(af[m], bf4[n], acc[m][n]);
    __builtin_amdgcn_s_setprio(0);
    bar();
    // ---- phase B: pure-register MFMA m=4..7; stage next B-half; counted vmcnt
    if (tile < NG-3) STAGE_B((tile+3)&3, tile+3);
    if (tile < NG-3)       asm volatile("s_waitcnt vmcnt(8)" ::: "memory");
    else if (tile == NG-3) asm volatile("s_waitcnt vmcnt(4)" ::: "memory");
    else if (tile == NG-2) asm volatile("s_waitcnt vmcnt(0)" ::: "memory");
    bar();
    __builtin_amdgcn_s_setprio(1);
    #pragma unroll
    for (int m = 0; m < 4; ++m)
      #pragma unroll
      for (int n = 0; n < 4; ++n)
        acc[4+m][n] = mfma16(ag[m], bf4[n], acc[4+m][n]);
    __builtin_amdgcn_s_setprio(0);
    bar();
  }
  #undef STAGE_A
  #undef STAGE_B

  float* outp = Cp + (size_t)split * (BATCH*OUTF);
  #pragma unroll
  for (int m = 0; m < 8; ++m){
    const int r0 = bm + wr*128 + m*16 + hi*4;
    #pragma unroll
    for (int n = 0; n < 4; ++n){
      const int cc = bn + wc*64 + n*16 + r15;
      #pragma unroll
      for (int j = 0; j < 4; ++j)
        outp[(size_t)(r0 + j) * OUTF + cc] = acc[m][n][j];
    }
  }
}

template<int NS>
__global__ __launch_bounds__(256) void reduceNS(const float* __restrict__ Cp,
                                                float* __restrict__ out){
  const size_t idx = ((size_t)blockIdx.x * 256 + threadIdx.x) * 4;
  f32x4 s = *(const f32x4*)(Cp + idx);
  #pragma unroll
  for (int p = 1; p < NS; ++p)
    s += *(const f32x4*)(Cp + (size_t)p * (BATCH*OUTF) + idx);
  *(f32x4*)(out + idx) = s;
}

// Correct-but-slow safety net if ws_size is tiny.
__global__ __launch_bounds__(256) void fallback(const float* __restrict__ x,
    const float* __restrict__ bw, const float* __restrict__ sw,
    const float* __restrict__ sc, float* __restrict__ out){
  const int b = blockIdx.x, t = threadIdx.x;
  __shared__ float ls[INF], sg[INF];
  __shared__ int   lc[INF];
  for (int i = t; i < INF; i += 256){
    float xx = x[(size_t)b*INF + i];
    ls[i] = xx / (1.0f + __expf(-xx));
    float tt = (xx + 1.0f)*2.5f;
    float fl = floorf(tt);
    int c = (int)fl + 3;
    lc[i] = ((unsigned)c < 11u) ? c : -1;
    sg[i] = __sinf(3.14159265358979f*(tt - fl));
  }
  __syncthreads();
  for (int o = t; o < OUTF; o += 256){
    float acc = 0.f;
    const float* bwr = bw + (size_t)o*INF;
    const float* swr = sw + (size_t)o*INF*KSPL;
    const float* scr = sc + (size_t)o*INF;
    for (int i = 0; i < INF; ++i){
      acc = fmaf(ls[i], bwr[i], acc);
      int c = lc[i];
      if (c >= 0) acc = fmaf(sg[i]*scr[i], swr[i*KSPL + c], acc);
    }
    out[(size_t)b*OUTF + o] = acc;
  }
}

extern "C" void kernel_launch(void* const* d_in, const int* in_sizes, int n_in,
                              void* d_out, int out_size, void* d_ws, size_t ws_size,
                              hipStream_t stream){
  const float* x  = (const float*)d_in[0];
  const float* bw = (const float*)d_in[1];
  const float* sw = (const float*)d_in[2];
  const float* sc = (const float*)d_in[3];
  float* out = (float*)d_out;
  const size_t szA = (size_t)BATCH * KTOT * 2;   // 100.7 MB
  const size_t szW = (size_t)OUTF  * KTOT * 2;   //  25.2 MB
  const size_t szC = (size_t)BATCH * OUTF * 4;   //  16.8 MB per split
  bf16*  A  = (bf16*)d_ws;
  bf16*  W  = (bf16*)((char*)d_ws + szA);
  float* Cp = (float*)((char*)d_ws + szA + szW);
  if (ws_size >= szA + szW + 4*szC){
    hipLaunchKernelGGL(gen_a,  dim3(BATCH), dim3(128), 0, stream, x, A);
    hipLaunchKernelGGL(pack_w, dim3(OUTF),  dim3(128), 0, stream, bw, sw, sc, W);
    gemm8p<4><<<dim3(256), dim3(512), 0, stream>>>(A, W, Cp);
    reduceNS<4><<<dim3(4096), dim3(256), 0, stream>>>(Cp, out);
  } else if (ws_size >= szA + szW + 3*szC){
    hipLaunchKernelGGL(gen_a,  dim3(BATCH), dim3(128), 0, stream, x, A);
    hipLaunchKernelGGL(pack_w, dim3(OUTF),  dim3(128), 0, stream, bw, sw, sc, W);
    gemm8p<3><<<dim3(192), dim3(512), 0, stream>>>(A, W, Cp);
    reduceNS<3><<<dim3(4096), dim3(256), 0, stream>>>(Cp, out);
  } else {
    hipLaunchKernelGGL(fallback, dim3(BATCH), dim3(256), 0, stream, x, bw, sw, sc, out);
  }
}